// Round 1
// 451.588 us; speedup vs baseline: 1.1049x; 1.1049x over previous
//
#include <hip/hip_runtime.h>

// GCN: 2x GCNConv(sym-norm, self-loops) + mean-pool + 2 MLP heads.
// R3: src-tile cache-blocked aggregation. binB fine-sorts each node's edge
// list by src>>15 (8 tiles x 2MB of h, each fits a 4MB XCD L2) and emits
// per-(node,tile) counts. agg kernels sweep tiles in lockstep (all 1024
// blocks co-resident, __syncthreads per tile) so concurrent gathers hit a
// 2MB window -> L2-miss traffic ~374MB -> ~190MB per agg pass.
// node2 (b1+leaky+@W2) is fused into agg1's epilogue via LDS transpose.

#define NBUCK 512          // coarse buckets = dst >> 9
#define BCAP  10240        // slack capacity per bucket (mean 8192, sigma ~90)
#define CHUNK 4096         // edges per pass-A block
#define NTILE 8            // src tiles = src >> 15 (2MB of h per tile)
#define TSH   15

__device__ __forceinline__ float leaky(float x) { return x > 0.f ? x : 0.01f * x; }

// --- Pass A: bin edges by dst>>9 into slack-capacity coarse buckets ------
__global__ __launch_bounds__(256) void
binA_kernel(const int* __restrict__ src, const int* __restrict__ dst,
            const float* __restrict__ ew, int* __restrict__ bucketCursor,
            int2* __restrict__ coarse, int E) {
    __shared__ int lhist[NBUCK], lbase[NBUCK], lcur[NBUCK], gbase[NBUCK];
    __shared__ int tmp[256];
    __shared__ int2 stag[CHUNK];
    __shared__ unsigned short sbuck[CHUNK];
    int t = threadIdx.x;
    int base = blockIdx.x * CHUNK;
    for (int b = t; b < NBUCK; b += 256) { lhist[b] = 0; lcur[b] = 0; }
    __syncthreads();
    int n = min(CHUNK, E - base);
    int myDst[16], mySrc[16]; float myEw[16];
#pragma unroll
    for (int k = 0; k < 16; ++k) {
        int j = t + k * 256;                       // coalesced
        if (j < n) {
            int d = dst[base + j];
            myDst[k] = d; mySrc[k] = src[base + j]; myEw[k] = ew[base + j];
            atomicAdd(&lhist[d >> 9], 1);
        } else myDst[k] = -1;
    }
    __syncthreads();
    // exclusive scan of lhist (512 entries, 256 threads, pair trick)
    tmp[t] = lhist[2 * t] + lhist[2 * t + 1];
    __syncthreads();
    for (int off = 1; off < 256; off <<= 1) {
        int v = (t >= off) ? tmp[t - off] : 0;
        __syncthreads();
        tmp[t] += v;
        __syncthreads();
    }
    int pb = (t == 0) ? 0 : tmp[t - 1];
    lbase[2 * t] = pb;
    lbase[2 * t + 1] = pb + lhist[2 * t];
    __syncthreads();
    // reserve global space per bucket (one atomic per non-empty bucket)
    for (int b = t; b < NBUCK; b += 256) {
        int c = lhist[b];
        gbase[b] = c ? atomicAdd(&bucketCursor[b], c) : 0;
    }
    // stage into LDS, sorted by bucket; pack (src | ldst<<18, ew)
    for (int k = 0; k < 16; ++k) {
        int d = myDst[k];
        if (d >= 0) {
            int b = d >> 9;
            int p = lbase[b] + atomicAdd(&lcur[b], 1);
            stag[p] = make_int2(mySrc[k] | ((d & 511) << 18), __float_as_int(myEw[k]));
            sbuck[p] = (unsigned short)b;
        }
    }
    __syncthreads();
    // write out: consecutive j -> consecutive addresses within bucket runs
    for (int j = t; j < n; j += 256) {
        int b = sbuck[j];
        coarse[(size_t)b * BCAP + gbase[b] + (j - lbase[b])] = stag[j];
    }
}

// --- scan bucket counts -> bucket bases (1 block x 512) ------------------
__global__ void bscan_kernel(const int* __restrict__ bucketCursor,
                             int* __restrict__ bucketBase, int* __restrict__ row,
                             int N, int E) {
    __shared__ int s[NBUCK];
    int t = threadIdx.x;
    int v = bucketCursor[t];
    s[t] = v;
    __syncthreads();
    for (int off = 1; off < NBUCK; off <<= 1) {
        int x = (t >= off) ? s[t - off] : 0;
        __syncthreads();
        s[t] += x;
        __syncthreads();
    }
    bucketBase[t] = s[t] - v;
    if (t == 0) row[N] = E;
}

// --- Pass B: fine sort within bucket by (local_dst, src_tile); -----------
// emits edata, row, dinv, and per-(node,tile) counts (ushort x8 packed).
__global__ __launch_bounds__(256) void
binB_kernel(const int* __restrict__ bucketCursor, const int* __restrict__ bucketBase,
            const int2* __restrict__ coarse, int2* __restrict__ edata,
            int* __restrict__ row, float* __restrict__ dinv,
            uint4* __restrict__ tcnt, int N) {
    __shared__ int loff[NBUCK * NTILE];     // counts, then in-place excl. offsets
    __shared__ int lcur[NBUCK * NTILE];
    __shared__ float ldeg[NBUCK];
    __shared__ int tmp[256];
    int b = blockIdx.x, t = threadIdx.x;
    for (int i = t; i < NBUCK * NTILE; i += 256) { loff[i] = 0; lcur[i] = 0; }
    for (int i = t; i < NBUCK; i += 256) ldeg[i] = 0.f;
    __syncthreads();
    int cnt = bucketCursor[b];
    const int2* cb = coarse + (size_t)b * BCAP;
    for (int j = t; j < cnt; j += 256) {
        int2 e = cb[j];
        int s = e.x & 0x3FFFF;
        int ld = (e.x >> 18) & 511;
        atomicAdd(&loff[(ld << 3) | (s >> TSH)], 1);
        atomicAdd(&ldeg[ld], __int_as_float(e.y));
    }
    __syncthreads();
    // in-place exclusive scan over 4096 bins (16 per thread)
    int idx0 = t * 16;
    int mysum = 0;
#pragma unroll
    for (int k = 0; k < 16; ++k) mysum += loff[idx0 + k];
    tmp[t] = mysum;
    __syncthreads();
    for (int off = 1; off < 256; off <<= 1) {
        int v = (t >= off) ? tmp[t - off] : 0;
        __syncthreads();
        tmp[t] += v;
        __syncthreads();
    }
    int run = tmp[t] - mysum;
#pragma unroll
    for (int k = 0; k < 16; ++k) { int v = loff[idx0 + k]; loff[idx0 + k] = run; run += v; }
    __syncthreads();
    int gb = bucketBase[b];
    for (int i = t; i < NBUCK; i += 256) {
        int node = b * NBUCK + i;
        int o[9];
#pragma unroll
        for (int k = 0; k < 8; ++k) o[k] = loff[i * 8 + k];
        o[8] = (i == NBUCK - 1) ? cnt : loff[i * 8 + 8];
        row[node] = gb + o[0];
        dinv[node] = rsqrtf(1.0f + ldeg[i]);     // +1 = self-loop weight
        uint4 p;
        p.x = (unsigned)(o[1] - o[0]) | ((unsigned)(o[2] - o[1]) << 16);
        p.y = (unsigned)(o[3] - o[2]) | ((unsigned)(o[4] - o[3]) << 16);
        p.z = (unsigned)(o[5] - o[4]) | ((unsigned)(o[6] - o[5]) << 16);
        p.w = (unsigned)(o[7] - o[6]) | ((unsigned)(o[8] - o[7]) << 16);
        tcnt[node] = p;
    }
    __syncthreads();
    for (int j = t; j < cnt; j += 256) {
        int2 e = cb[j];
        int s = e.x & 0x3FFFF;
        int ld = (e.x >> 18) & 511;
        int key = (ld << 3) | (s >> TSH);
        int pos = gb + loff[key] + atomicAdd(&lcur[key], 1);
        edata[pos] = make_int2(s, e.y);
    }
}

// --- node pass 1: h1 = X@W1 ----------------------------------------------
__global__ void node1_kernel(const float* __restrict__ X, const float* __restrict__ W1,
                             float* __restrict__ h, int N) {
    __shared__ float w[48];
    if (threadIdx.x < 48) w[threadIdx.x] = W1[threadIdx.x];
    __syncthreads();
    int i = blockIdx.x * blockDim.x + threadIdx.x;
    if (i >= N) return;
    float x0 = X[3 * i], x1 = X[3 * i + 1], x2 = X[3 * i + 2];
    float4* hp = (float4*)(h + (size_t)i * 16);
#pragma unroll
    for (int k = 0; k < 4; ++k) {
        float4 v;
        v.x = x0 * w[4 * k + 0] + x1 * w[16 + 4 * k + 0] + x2 * w[32 + 4 * k + 0];
        v.y = x0 * w[4 * k + 1] + x1 * w[16 + 4 * k + 1] + x2 * w[32 + 4 * k + 1];
        v.z = x0 * w[4 * k + 2] + x1 * w[16 + 4 * k + 2] + x2 * w[32 + 4 * k + 2];
        v.w = x0 * w[4 * k + 3] + x1 * w[16 + 4 * k + 3] + x2 * w[32 + 4 * k + 3];
        hp[k] = v;
    }
}

// --- agg pass 1, tile-phased, fused with node2 (b1+leaky+@W2) ------------
// 512 threads = 128 node-groups x 4 lanes; 2 nodes per group (i, i+128).
// Grid = N/256 = 1024 blocks -> all co-resident (4 blocks/CU) so the
// per-tile __syncthreads keeps every XCD's gathers inside one 2MB tile.
__global__ __launch_bounds__(512) void
aggA_kernel(const int* __restrict__ row, const uint4* __restrict__ tcnt,
            const int2* __restrict__ edata, const float* __restrict__ dinv,
            const float* __restrict__ h, const float* __restrict__ b1,
            const float* __restrict__ W2, float* __restrict__ h2) {
    __shared__ float w[256];
    __shared__ float bb[16];
    __shared__ float sx[128][17];
    int t = threadIdx.x;
    if (t < 256) w[t] = W2[t];
    else if (t < 272) bb[t - 256] = b1[t - 256];
    int ln = t >> 2, l = t & 3;
    int iA = blockIdx.x * 256 + ln, iB = iA + 128;
    const float4* hp = (const float4*)h;
    int eA = row[iA], eB = row[iB];
    uint4 cAv = tcnt[iA], cBv = tcnt[iB];
    unsigned ca[4] = {cAv.x, cAv.y, cAv.z, cAv.w};
    unsigned cb[4] = {cBv.x, cBv.y, cBv.z, cBv.w};
    float diA = dinv[iA], diB = dinv[iB];
    float4 vA = hp[(size_t)iA * 4 + l], vB = hp[(size_t)iB * 4 + l];
    float dA2 = diA * diA, dB2 = diB * diB;
    float4 accA = make_float4(vA.x * dA2, vA.y * dA2, vA.z * dA2, vA.w * dA2);
    float4 accB = make_float4(vB.x * dB2, vB.y * dB2, vB.z * dB2, vB.w * dB2);
#pragma unroll
    for (int tt = 0; tt < NTILE; ++tt) {
        int nA = (ca[tt >> 1] >> ((tt & 1) * 16)) & 0xFFFF;
        int nB = (cb[tt >> 1] >> ((tt & 1) * 16)) & 0xFFFF;
        for (int e = eA + nA; eA < e; ++eA) {
            int2 ed = edata[eA];
            float nrm = dinv[ed.x] * __int_as_float(ed.y) * diA;
            float4 v = hp[(size_t)ed.x * 4 + l];
            accA.x += v.x * nrm; accA.y += v.y * nrm; accA.z += v.z * nrm; accA.w += v.w * nrm;
        }
        for (int e = eB + nB; eB < e; ++eB) {
            int2 ed = edata[eB];
            float nrm = dinv[ed.x] * __int_as_float(ed.y) * diB;
            float4 v = hp[(size_t)ed.x * 4 + l];
            accB.x += v.x * nrm; accB.y += v.y * nrm; accB.z += v.z * nrm; accB.w += v.w * nrm;
        }
        __syncthreads();
    }
    // fused node2: x = leaky(acc + b1); h2 = x@W2 (LDS transpose, padded)
    sx[ln][4 * l + 0] = leaky(accA.x + bb[4 * l + 0]);
    sx[ln][4 * l + 1] = leaky(accA.y + bb[4 * l + 1]);
    sx[ln][4 * l + 2] = leaky(accA.z + bb[4 * l + 2]);
    sx[ln][4 * l + 3] = leaky(accA.w + bb[4 * l + 3]);
    __syncthreads();
    {
        float a0 = 0.f, a1 = 0.f, a2 = 0.f, a3 = 0.f;
#pragma unroll
        for (int q = 0; q < 16; ++q) {
            float xv = sx[ln][q];
            a0 += xv * w[q * 16 + 4 * l + 0];
            a1 += xv * w[q * 16 + 4 * l + 1];
            a2 += xv * w[q * 16 + 4 * l + 2];
            a3 += xv * w[q * 16 + 4 * l + 3];
        }
        ((float4*)h2)[(size_t)iA * 4 + l] = make_float4(a0, a1, a2, a3);
    }
    __syncthreads();
    sx[ln][4 * l + 0] = leaky(accB.x + bb[4 * l + 0]);
    sx[ln][4 * l + 1] = leaky(accB.y + bb[4 * l + 1]);
    sx[ln][4 * l + 2] = leaky(accB.z + bb[4 * l + 2]);
    sx[ln][4 * l + 3] = leaky(accB.w + bb[4 * l + 3]);
    __syncthreads();
    {
        float a0 = 0.f, a1 = 0.f, a2 = 0.f, a3 = 0.f;
#pragma unroll
        for (int q = 0; q < 16; ++q) {
            float xv = sx[ln][q];
            a0 += xv * w[q * 16 + 4 * l + 0];
            a1 += xv * w[q * 16 + 4 * l + 1];
            a2 += xv * w[q * 16 + 4 * l + 2];
            a3 += xv * w[q * 16 + 4 * l + 3];
        }
        ((float4*)h2)[(size_t)iB * 4 + l] = make_float4(a0, a1, a2, a3);
    }
}

// --- agg pass 2, tile-phased (pool applies b2+leaky) ---------------------
__global__ __launch_bounds__(512) void
aggB_kernel(const int* __restrict__ row, const uint4* __restrict__ tcnt,
            const int2* __restrict__ edata, const float* __restrict__ dinv,
            const float* __restrict__ h2, float* __restrict__ agg2) {
    int t = threadIdx.x;
    int ln = t >> 2, l = t & 3;
    int iA = blockIdx.x * 256 + ln, iB = iA + 128;
    const float4* hp = (const float4*)h2;
    int eA = row[iA], eB = row[iB];
    uint4 cAv = tcnt[iA], cBv = tcnt[iB];
    unsigned ca[4] = {cAv.x, cAv.y, cAv.z, cAv.w};
    unsigned cb[4] = {cBv.x, cBv.y, cBv.z, cBv.w};
    float diA = dinv[iA], diB = dinv[iB];
    float4 vA = hp[(size_t)iA * 4 + l], vB = hp[(size_t)iB * 4 + l];
    float dA2 = diA * diA, dB2 = diB * diB;
    float4 accA = make_float4(vA.x * dA2, vA.y * dA2, vA.z * dA2, vA.w * dA2);
    float4 accB = make_float4(vB.x * dB2, vB.y * dB2, vB.z * dB2, vB.w * dB2);
#pragma unroll
    for (int tt = 0; tt < NTILE; ++tt) {
        int nA = (ca[tt >> 1] >> ((tt & 1) * 16)) & 0xFFFF;
        int nB = (cb[tt >> 1] >> ((tt & 1) * 16)) & 0xFFFF;
        for (int e = eA + nA; eA < e; ++eA) {
            int2 ed = edata[eA];
            float nrm = dinv[ed.x] * __int_as_float(ed.y) * diA;
            float4 v = hp[(size_t)ed.x * 4 + l];
            accA.x += v.x * nrm; accA.y += v.y * nrm; accA.z += v.z * nrm; accA.w += v.w * nrm;
        }
        for (int e = eB + nB; eB < e; ++eB) {
            int2 ed = edata[eB];
            float nrm = dinv[ed.x] * __int_as_float(ed.y) * diB;
            float4 v = hp[(size_t)ed.x * 4 + l];
            accB.x += v.x * nrm; accB.y += v.y * nrm; accB.z += v.z * nrm; accB.w += v.w * nrm;
        }
        __syncthreads();
    }
    ((float4*)agg2)[(size_t)iA * 4 + l] = accA;
    ((float4*)agg2)[(size_t)iB * 4 + l] = accB;
}

// --- tiny MLP head: 16 ->16 ->16 ->2 -------------------------------------
__device__ void head_mlp(const float* pooled,
                         const float* __restrict__ Wa, const float* __restrict__ ba,
                         const float* __restrict__ Wb, const float* __restrict__ bb,
                         const float* __restrict__ Wc, const float* __restrict__ bc,
                         float* o) {
    float t[16], u[16];
#pragma unroll
    for (int f = 0; f < 16; ++f) {
        float a = ba[f];
        for (int k = 0; k < 16; ++k) a += pooled[k] * Wa[k * 16 + f];
        t[f] = leaky(a);
    }
#pragma unroll
    for (int f = 0; f < 16; ++f) {
        float a = bb[f];
        for (int k = 0; k < 16; ++k) a += t[k] * Wb[k * 16 + f];
        u[f] = leaky(a);
    }
    float o0 = bc[0], o1 = bc[1];
    for (int k = 0; k < 16; ++k) { o0 += u[k] * Wc[2 * k]; o1 += u[k] * Wc[2 * k + 1]; }
    o[0] = o0; o[1] = o1;
}

// --- pool (block per graph; Batching sorted -> binary search) + heads ----
__global__ void pool_head_kernel(const float* __restrict__ agg2, const float* __restrict__ b2,
                                 const int* __restrict__ batching, int N,
                                 const float* __restrict__ Wp1, const float* __restrict__ bp1,
                                 const float* __restrict__ Wp2, const float* __restrict__ bp2,
                                 const float* __restrict__ Wp3, const float* __restrict__ bp3,
                                 const float* __restrict__ Wt1, const float* __restrict__ bt1,
                                 const float* __restrict__ Wt2, const float* __restrict__ bt2,
                                 const float* __restrict__ Wt3, const float* __restrict__ bt3,
                                 float* __restrict__ out) {
    int g = blockIdx.x;
    __shared__ int bounds[2];
    if (threadIdx.x < 2) {
        int v = g + (int)threadIdx.x;
        int lo = 0, hi = N;
        while (lo < hi) { int m = (lo + hi) >> 1; if (batching[m] < v) lo = m + 1; else hi = m; }
        bounds[threadIdx.x] = lo;
    }
    __syncthreads();
    int lo = bounds[0], hi = bounds[1];
    int f = threadIdx.x & 15, r = threadIdx.x >> 4;    // 16 rows x 16 features
    float bf = b2[f];
    float acc = 0.f;
    for (int i = lo + r; i < hi; i += 16) acc += leaky(agg2[(size_t)i * 16 + f] + bf);
    __shared__ float red[16][17];
    red[r][f] = acc;
    __syncthreads();
    __shared__ float pooled[16];
    if (r == 0) {
        float s = 0.f;
#pragma unroll
        for (int k = 0; k < 16; ++k) s += red[k][f];
        pooled[f] = s / fmaxf((float)(hi - lo), 1.0f);
    }
    __syncthreads();
    if (threadIdx.x == 0) {
        float o[2];
        head_mlp(pooled, Wp1, bp1, Wp2, bp2, Wp3, bp3, o);
        out[4 * g + 0] = o[0]; out[4 * g + 1] = o[1];
    } else if (threadIdx.x == 1) {
        float o[2];
        head_mlp(pooled, Wt1, bt1, Wt2, bt2, Wt3, bt3, o);
        out[4 * g + 2] = o[0]; out[4 * g + 3] = o[1];
    }
}

extern "C" void kernel_launch(void* const* d_in, const int* in_sizes, int n_in,
                              void* d_out, int out_size, void* d_ws, size_t ws_size,
                              hipStream_t stream) {
    const float* X        = (const float*)d_in[0];
    const int*   ei       = (const int*)d_in[1];
    const float* ew       = (const float*)d_in[2];
    const int*   batching = (const int*)d_in[3];
    const float* W1  = (const float*)d_in[5];  const float* b1  = (const float*)d_in[6];
    const float* W2  = (const float*)d_in[7];  const float* b2  = (const float*)d_in[8];
    const float* Wp1 = (const float*)d_in[9];  const float* bp1 = (const float*)d_in[10];
    const float* Wp2 = (const float*)d_in[11]; const float* bp2 = (const float*)d_in[12];
    const float* Wp3 = (const float*)d_in[13]; const float* bp3 = (const float*)d_in[14];
    const float* Wt1 = (const float*)d_in[15]; const float* bt1 = (const float*)d_in[16];
    const float* Wt2 = (const float*)d_in[17]; const float* bt2 = (const float*)d_in[18];
    const float* Wt3 = (const float*)d_in[19]; const float* bt3 = (const float*)d_in[20];

    const int N = in_sizes[3];        // 262144 = 512 * 512
    const int E = in_sizes[2];        // 4194304
    const int G = out_size / 4;       // 1024
    const int* src = ei;
    const int* dst = ei + E;

    char* ws = (char*)d_ws;
    size_t off = 0;
    int2*  edata = (int2*)(ws + off);  off += (size_t)E * 8;              // 32 MB fine CSR
    char*  regionA = ws + off;         off += (size_t)N * 64 * 3;         // 48 MB
    // regionA phase 1: coarse buckets (40 MB); phase 2: h | h2 | agg2
    int2*  coarse = (int2*)regionA;
    float* h      = (float*)regionA;
    float* h2     = (float*)(regionA + (size_t)N * 64);
    float* agg2   = (float*)(regionA + (size_t)N * 128);
    int*   bucketCursor = (int*)(ws + off); off += NBUCK * 4;
    int*   bucketBase   = (int*)(ws + off); off += NBUCK * 4;
    int*   row   = (int*)(ws + off);   off += (size_t)(N + 4) * 4;
    float* dinv  = (float*)(ws + off); off += (size_t)N * 4;
    uint4* tcnt  = (uint4*)(ws + off); off += (size_t)N * 16;             // 4 MB
    float* out   = (float*)d_out;

    hipMemsetAsync(bucketCursor, 0, NBUCK * 4, stream);

    const int tb = 256;
    binA_kernel<<<(E + CHUNK - 1) / CHUNK, tb, 0, stream>>>(src, dst, ew, bucketCursor, coarse, E);
    bscan_kernel<<<1, NBUCK, 0, stream>>>(bucketCursor, bucketBase, row, N, E);
    binB_kernel<<<NBUCK, tb, 0, stream>>>(bucketCursor, bucketBase, coarse, edata, row, dinv, tcnt, N);
    node1_kernel<<<(N + tb - 1) / tb, tb, 0, stream>>>(X, W1, h, N);
    aggA_kernel<<<N / 256, 512, 0, stream>>>(row, tcnt, edata, dinv, h, b1, W2, h2);
    aggB_kernel<<<N / 256, 512, 0, stream>>>(row, tcnt, edata, dinv, h2, agg2);
    pool_head_kernel<<<G, tb, 0, stream>>>(agg2, b2, batching, N,
                                           Wp1, bp1, Wp2, bp2, Wp3, bp3,
                                           Wt1, bt1, Wt2, bt2, Wt3, bt3, out);
}